// Round 2
// baseline (390.788 us; speedup 1.0000x reference)
//
#include <hip/hip_runtime.h>
#include <float.h>

// SearchTransfer MI355X — R12: k_mfma chunk loop phase-split (T3+T5).
// Post-mortem R11: counted-vmcnt regressed (186->195us) -> DMA drain was
// never the cost. Per-CU arithmetic: MFMA 3725 cyc/chunk, LDS-read pipe
// ~3072 cyc/chunk, wall 8140 -> pipes SERIALIZED (barrier-aligned waves
// alternate read-burst / MFMA-burst). Fix per m201/m218b/m224: split each
// chunk into 3 phases {reads + DMA issue -> barrier -> lgkm(0) ->
// setprio(1) -> 16 MFMA -> setprio(0) -> barrier} so waves drift within a
// phase and LDS + MFMA pipes overlap. Depth-1 prefetch (R10 schedule):
// issue ch+1 into the NOT-being-read buffer during P1/P2; chunk-top
// vmcnt(0) is free (issued a full chunk earlier). k_pack2 + k_foldmerge
// unchanged (control).
// Split-f16 3-term GEMM (K'=320), top-2 guard tau=2^-6, pruned exact fixup.
// B=2, C=16, H=W=96, k=3,pad=1,stride=1, lv=2. L=9216, KF=144.
// out = [T_org (2*16*192*192 f32), S (2*9216 as f32)]

#define BATCH 2
#define CCH   16
#define HH    96
#define WW    96
#define LP    9216
#define KF    144
#define K3    320      // 5 chunks x 64 k' ; chunk = [hi32|lo32] of k-slice
#define OH    192
#define OW    192
#define NRT2  36       // row tiles of 256
#define NCB2  36       // col blocks of 256

typedef _Float16 f16;
typedef __attribute__((ext_vector_type(8))) _Float16 f16x8;
typedef __attribute__((ext_vector_type(4))) float    f32x4;

__device__ __forceinline__ void async16(const void* g, void* l) {
    __builtin_amdgcn_global_load_lds(
        (const __attribute__((address_space(1))) void*)g,
        (__attribute__((address_space(3))) void*)l, 16, 0, 0);
}

// ---------------------------------------------------- fused norm + pack ----
// UNCHANGED. Block = (py, batch, side*4+quarter). Norms bit-identical
// (zero-padded terms exact); writes 24 rows x 40 granules, layout:
// granule g: slice=g>>3, half=(g>>2)&1, j=g&3.
__global__ __launch_bounds__(256) void k_pack2(
        const float* __restrict__ ref, const float* __restrict__ lr,
        float* __restrict__ rinv, float* __restrict__ bns,
        f16* __restrict__ Abig, f16* __restrict__ Bbig) {
    __shared__ float imgS[CCH][3][26];   // x origin at global xi = q*24-1
    __shared__ float scl[24];
    int py = blockIdx.x, b = blockIdx.y;
    int side = blockIdx.z >> 2, q = blockIdx.z & 3;
    int tid = threadIdx.x;
    const float* img = (side ? lr : ref) + (size_t)b * CCH * HH * WW;

    for (int i = tid; i < CCH * 3 * 26; i += 256) {
        int c = i / 78, rem = i - c * 78;
        int rr = rem / 26, xx = rem - rr * 26;
        int y = py + rr - 1, xi = q * 24 - 1 + xx;
        float v = 0.f;
        if ((unsigned)y < (unsigned)HH && (unsigned)xi < (unsigned)WW)
            v = img[(c * HH + y) * WW + xi];
        imgS[c][rr][xx] = v;
    }
    __syncthreads();

    if (tid < 24) {
        int pxl = tid;
        float s = 0.f;
        for (int c = 0; c < CCH; ++c)
            #pragma unroll
            for (int dy = 0; dy < 3; ++dy)
                #pragma unroll
                for (int dx = 0; dx < 3; ++dx) {
                    float v = imgS[c][dy][pxl + dx];   // 0 when OOB: exact
                    s += v * v;
                }
        int gl = b * LP + py * 96 + q * 24 + pxl;
        if (side) { bns[gl] = 1024.0f * sqrtf(s); scl[pxl] = 1024.0f; }
        else { float r = 1.0f / fmaxf(sqrtf(s), 1e-12f); rinv[gl] = r; scl[pxl] = 1024.0f * r; }
    }
    __syncthreads();

    f16* dstb = (side ? Bbig : Abig) + (size_t)(b * LP + py * 96 + q * 24) * K3;
    for (int i = tid; i < 24 * 40; i += 256) {          // 40 granules/row
        int pxl = i / 40, g = i - pxl * 40;
        int chunk = g >> 3, half = (g >> 2) & 1, j = g & 3;
        int f0 = chunk * 32 + j * 8;                    // original k base
        float sc = scl[pxl];
        f16x8 o;
        #pragma unroll
        for (int e = 0; e < 8; ++e) {
            int f = f0 + e;                             // 0..159 (>=144 pad)
            float v = 0.f;
            if (f < KF) {
                int c = f / 9, r9 = f - c * 9;
                int dy = r9 / 3, dx = r9 - dy * 3;
                v = imgS[c][dy][pxl + dx] * sc;
            }
            f16 h = (f16)v;
            o[e] = half ? (f16)(v - (float)h) : h;
        }
        *(f16x8*)(dstb + (size_t)pxl * K3 + g * 8) = o;
    }
}

// -------------------------------------------------- MFMA GEMM + top-2 ------
// R12: 3-phase chunk schedule. Per chunk: top {vmcnt(0); barrier} (ch data
// ready; free since issue was a full chunk earlier). P1 {read af0,bf0; issue
// 2 DMA ch+1 -> other buf}, P2 {read bf1; issue 2 DMA}, P3 {read af1}; each
// phase then {barrier; lgkm(0); sched_barrier; setprio(1); 16 MFMA;
// setprio(0); barrier}. Hazards: DMA always targets the buffer NOT read
// this chunk; all reads of a buffer complete before the chunk-top barrier
// that precedes its next overwrite (lgkm(0) before MFMA, in-order issue).
__global__ __launch_bounds__(1024) void k_mfma(
        const f16* __restrict__ Abig, const f16* __restrict__ Bbig,
        float* __restrict__ pv1, int* __restrict__ pi1, float* __restrict__ pv2) {
    __shared__ f16 smem[2][512 * 64];                  // 128 KB; rows 0-255=A, 256-511=B
    int tid = threadIdx.x, lane = tid & 63, w = tid >> 6;   // w: 0..15
    int wm = w & 3, wn = w >> 2;
    int l15 = lane & 15, quad = lane >> 4, l7 = lane & 7;

    int i = blockIdx.x;                // 0..2591
    int xcd = i & 7, slot = i >> 3;    // slot 0..323
    int cb = slot / 9;                 // col tile 0..35 (major)
    int brt = xcd * 9 + (slot - cb * 9);   // 0..71
    int b = brt / NRT2, rt = brt - b * NRT2;
    int r0 = rt * 256, c0 = cb * 256;

    int srow = lane >> 3;              // row within group
    int sg   = (lane & 7) ^ srow;      // source granule (self-inverse swizzle)
    const f16* gsrc[4];
    int ldsbyte[4];                    // wave-uniform byte offset in one buffer
    #pragma unroll
    for (int j = 0; j < 4; ++j) {
        int G = w * 4 + j;             // 0..63
        int row8 = G * 8 + srow;       // 0..511 (A rows then B rows)
        const f16* base = (row8 < 256)
            ? Abig + (size_t)(b * LP + r0 + row8) * K3
            : Bbig + (size_t)(b * LP + c0 + (row8 - 256)) * K3;
        gsrc[j] = base + sg * 8;
        ldsbyte[j] = G * 1024;         // G*8 rows * 128 B/row
    }
    int arow[4], brow[4];              // frag row byte offsets (row stride 128 B)
    #pragma unroll
    for (int t = 0; t < 4; ++t) {
        arow[t] = (wm * 64 + t * 16 + l15) * 128;
        brow[t] = (256 + wn * 64 + t * 16 + l15) * 128;
    }
    int ph0 = ((quad) ^ l7) << 4;          // ks=0 granules: hi slice
    int ph1 = ((4 + quad) ^ l7) << 4;      // ks=1 granules: lo slice

    f32x4 acc[4][4];
    #pragma unroll
    for (int ii = 0; ii < 4; ++ii)
        #pragma unroll
        for (int j = 0; j < 4; ++j) { acc[ii][j][0]=0.f; acc[ii][j][1]=0.f; acc[ii][j][2]=0.f; acc[ii][j][3]=0.f; }

    // prologue: chunk 0 -> buf 0
    #pragma unroll
    for (int j = 0; j < 4; ++j) async16(gsrc[j], (char*)smem[0] + ldsbyte[j]);

    for (int ch = 0; ch < 5; ++ch) {
        asm volatile("s_waitcnt vmcnt(0)" ::: "memory");   // ch's DMA landed (own)
        __builtin_amdgcn_s_barrier();                      // ...and everyone's
        const char* buf = (const char*)smem[ch & 1];
        char* nbuf = (char*)smem[(ch + 1) & 1];
        f16x8 af0[4], bf0[4], bf1[4], af1[4];

        // ---- phase 1: reads af0,bf0 + 2 DMA; MFMA hi*hi ----
        #pragma unroll
        for (int t = 0; t < 4; ++t) af0[t] = *(const f16x8*)(buf + arow[t] + ph0);
        #pragma unroll
        for (int t = 0; t < 4; ++t) bf0[t] = *(const f16x8*)(buf + brow[t] + ph0);
        if (ch < 4) {
            async16(gsrc[0] + (ch + 1) * 64, nbuf + ldsbyte[0]);
            async16(gsrc[1] + (ch + 1) * 64, nbuf + ldsbyte[1]);
        }
        __builtin_amdgcn_s_barrier();
        asm volatile("s_waitcnt lgkmcnt(0)" ::: "memory");
        __builtin_amdgcn_sched_barrier(0);
        __builtin_amdgcn_s_setprio(1);
        #pragma unroll
        for (int rtt = 0; rtt < 4; ++rtt)
            #pragma unroll
            for (int ct = 0; ct < 4; ++ct)
                acc[rtt][ct] = __builtin_amdgcn_mfma_f32_16x16x32_f16(af0[rtt], bf0[ct], acc[rtt][ct], 0, 0, 0);
        __builtin_amdgcn_s_setprio(0);
        __builtin_amdgcn_s_barrier();

        // ---- phase 2: reads bf1 + 2 DMA; MFMA hi*lo ----
        #pragma unroll
        for (int t = 0; t < 4; ++t) bf1[t] = *(const f16x8*)(buf + brow[t] + ph1);
        if (ch < 4) {
            async16(gsrc[2] + (ch + 1) * 64, nbuf + ldsbyte[2]);
            async16(gsrc[3] + (ch + 1) * 64, nbuf + ldsbyte[3]);
        }
        __builtin_amdgcn_s_barrier();
        asm volatile("s_waitcnt lgkmcnt(0)" ::: "memory");
        __builtin_amdgcn_sched_barrier(0);
        __builtin_amdgcn_s_setprio(1);
        #pragma unroll
        for (int rtt = 0; rtt < 4; ++rtt)
            #pragma unroll
            for (int ct = 0; ct < 4; ++ct)
                acc[rtt][ct] = __builtin_amdgcn_mfma_f32_16x16x32_f16(af0[rtt], bf1[ct], acc[rtt][ct], 0, 0, 0);
        __builtin_amdgcn_s_setprio(0);
        __builtin_amdgcn_s_barrier();

        // ---- phase 3: reads af1; MFMA lo*hi ----
        #pragma unroll
        for (int t = 0; t < 4; ++t) af1[t] = *(const f16x8*)(buf + arow[t] + ph1);
        __builtin_amdgcn_s_barrier();
        asm volatile("s_waitcnt lgkmcnt(0)" ::: "memory");
        __builtin_amdgcn_sched_barrier(0);
        __builtin_amdgcn_s_setprio(1);
        #pragma unroll
        for (int rtt = 0; rtt < 4; ++rtt)
            #pragma unroll
            for (int ct = 0; ct < 4; ++ct)
                acc[rtt][ct] = __builtin_amdgcn_mfma_f32_16x16x32_f16(af1[rtt], bf0[ct], acc[rtt][ct], 0, 0, 0);
        __builtin_amdgcn_s_setprio(0);
        __builtin_amdgcn_s_barrier();
    }
    __syncthreads();                   // smem reads done -> overlay epilogue scratch

    float* sv1 = (float*)smem;                         // [4][256]
    int*   si1 = (int*)  ((char*)smem + 4096);
    float* sv2 = (float*)((char*)smem + 8192);

    int rbase = r0 + wm * 64 + (quad << 2);
    #pragma unroll
    for (int ct = 0; ct < 4; ++ct) {
        float v1 = -FLT_MAX, v2 = -FLT_MAX; int i1 = 0;
        #pragma unroll
        for (int rtt = 0; rtt < 4; ++rtt)
            #pragma unroll
            for (int e = 0; e < 4; ++e) {              // ascending rows; strict > = first wins
                float v = acc[rtt][ct][e];
                int rg = rbase + rtt * 16 + e;
                if (v > v1) { v2 = v1; v1 = v; i1 = rg; }
                else if (v > v2) v2 = v;
            }
        #pragma unroll
        for (int off = 16; off < 64; off <<= 1) {      // reduce over quad (rows)
            float ov1 = __shfl_xor(v1, off, 64);
            int   oi1 = __shfl_xor(i1, off, 64);
            float ov2 = __shfl_xor(v2, off, 64);
            if (ov1 > v1 || (ov1 == v1 && oi1 < i1)) { v2 = fmaxf(v1, ov2); v1 = ov1; i1 = oi1; }
            else v2 = fmaxf(v2, ov1);
        }
        if (quad == 0) {
            int col = wn * 64 + ct * 16 + l15;
            sv1[wm * 256 + col] = v1; si1[wm * 256 + col] = i1; sv2[wm * 256 + col] = v2;
        }
    }
    __syncthreads();
    if (tid < 256) {
        int col = tid;
        float v1 = sv1[col]; int i1 = si1[col]; float v2 = sv2[col];
        #pragma unroll
        for (int m = 1; m < 4; ++m) {                  // ascending wm = ascending rows
            float ov1 = sv1[m * 256 + col]; int oi1 = si1[m * 256 + col]; float ov2 = sv2[m * 256 + col];
            if (ov1 > v1) { v2 = fmaxf(v1, ov2); v1 = ov1; i1 = oi1; }
            else v2 = fmaxf(v2, ov1);
        }
        size_t o = ((size_t)(b * NRT2 + rt)) * LP + c0 + col;
        pv1[o] = v1; pi1[o] = i1; pv2[o] = v2;
    }
}

// -------------------------------------- fused merge + fixup + fold ---------
// UNCHANGED. Block = (b, 16x16 pixel tile, all 16 channels). Phase A: merge
// the <=10x10 patch neighborhood (ascending rc = first-wins ties; flag iff
// gap < tau = bns*2^-6); owner patches (center pixel in tile) write Sout.
// Phase B: exact pruned fp32 argmax for flagged patches (rare; duplicated
// across <=4 neighbor blocks, idempotent). Phase C: fold with S from LDS,
// 9-patch base reused across 16 channels.
__global__ __launch_bounds__(256) void k_foldmerge(
        const float* __restrict__ refimg, const float* __restrict__ lrimg,
        const float* __restrict__ rinv,
        const float* __restrict__ pv1, const int* __restrict__ pi1,
        const float* __restrict__ pv2, const float* __restrict__ bns,
        const float* __restrict__ org,
        float* __restrict__ outT, float* __restrict__ Sout) {
    __shared__ int   s_S[10][10];
    __shared__ int   s_flag[100];
    __shared__ int   s_nflag;
    __shared__ float bcol[KF];
    __shared__ float spv[NRT2];
    __shared__ float red[4]; __shared__ int redi[4];
    int tx = blockIdx.x, ty = blockIdx.y, b = blockIdx.z;
    int x0 = tx * 16, y0 = ty * 16;
    int lhb = 8 * ty - 1; if (lhb < 0) lhb = 0;
    int lwb = 8 * tx - 1; if (lwb < 0) lwb = 0;
    int lhe = 8 * ty + 8; if (lhe > 95) lhe = 95;
    int lwe = 8 * tx + 8; if (lwe > 95) lwe = 95;
    int tid = threadIdx.x;

    if (tid == 0) s_nflag = 0;
    __syncthreads();

    // ---- Phase A: merge ----
    if (tid < 100) {
        int ph = tid / 10, pw = tid - ph * 10;
        int lh = lhb + ph, lw = lwb + pw;
        if (lh <= lhe && lw <= lwe) {
            int col = lh * 96 + lw;
            float v1 = -FLT_MAX, v2 = -FLT_MAX; int i1 = 0;
            for (int rc = 0; rc < NRT2; ++rc) {        // ascending: first-wins
                size_t o = ((size_t)(b * NRT2 + rc)) * LP + col;
                float cv1 = pv1[o]; int ci1 = pi1[o]; float cv2 = pv2[o];
                if (cv1 > v1) { v2 = fmaxf(v1, cv2); v1 = cv1; i1 = ci1; }
                else v2 = fmaxf(v2, cv1);
            }
            s_S[ph][pw] = i1;
            float tau = bns[b * LP + col] * 0.015625f; // 2^-6
            if (v1 - v2 < tau) { int k = atomicAdd(&s_nflag, 1); s_flag[k] = tid; }
            if (lh >= 8 * ty && lh < 8 * ty + 8 && lw >= 8 * tx && lw < 8 * tx + 8)
                Sout[b * LP + col] = (float)i1;        // owner write (partition)
        }
    }
    __syncthreads();

    // ---- Phase B: exact fixup for flagged patches (rare) ----
    int nf = s_nflag;
    for (int fi = 0; fi < nf; ++fi) {
        int pt = s_flag[fi];
        int ph = pt / 10, pw = pt - ph * 10;
        int lh = lhb + ph, lw = lwb + pw;
        int col = lh * 96 + lw, gid = b * LP + col;
        __syncthreads();                               // protect bcol/spv reuse
        if (tid < KF) {
            int c = tid / 9, r = tid - c * 9;
            int dy = r / 3, dx = r - dy * 3;
            int y = lh + dy - 1, x = lw + dx - 1;
            float v = 0.f;
            if ((unsigned)y < (unsigned)HH && (unsigned)x < (unsigned)WW)
                v = lrimg[((size_t)(b * CCH + c) * HH + y) * WW + x];
            bcol[tid] = v;
        }
        if (tid < NRT2) spv[tid] = pv1[((size_t)(b * NRT2 + tid)) * LP + col];
        __syncthreads();
        float v1 = -FLT_MAX;
        for (int rc = 0; rc < NRT2; ++rc) v1 = fmaxf(v1, spv[rc]);
        float thresh = v1 - bns[gid] * 0.015625f;
        float best = -FLT_MAX; int bi = 0x7fffffff;
        for (int rc = 0; rc < NRT2; ++rc) {            // ascending rows
            if (spv[rc] < thresh) continue;            // prune (uniform)
            int row = rc * 256 + tid;
            int py = row / WW, px = row - py * WW;
            float s = 0.f;
            for (int c = 0; c < CCH; ++c) {
                const float* ic = refimg + (size_t)(b * CCH + c) * HH * WW;
                #pragma unroll
                for (int dy = 0; dy < 3; ++dy) {
                    int y = py + dy - 1;
                    if ((unsigned)y >= (unsigned)HH) continue;
                    #pragma unroll
                    for (int dx = 0; dx < 3; ++dx) {
                        int x = px + dx - 1;
                        if ((unsigned)x >= (unsigned)WW) continue;
                        s = fmaf(ic[y * WW + x], bcol[c * 9 + dy * 3 + dx], s);
                    }
                }
            }
            s *= rinv[b * LP + row];
            if (s > best || (s == best && row < bi)) { best = s; bi = row; }
        }
        #pragma unroll
        for (int off = 1; off < 64; off <<= 1) {
            float ov = __shfl_xor(best, off, 64);
            int   oi = __shfl_xor(bi, off, 64);
            if (ov > best || (ov == best && oi < bi)) { best = ov; bi = oi; }
        }
        if ((tid & 63) == 0) { red[tid >> 6] = best; redi[tid >> 6] = bi; }
        __syncthreads();
        if (tid == 0) {
            float b0 = red[0]; int i0 = redi[0];
            for (int k = 1; k < 4; ++k)
                if (red[k] > b0 || (red[k] == b0 && redi[k] < i0)) { b0 = red[k]; i0 = redi[k]; }
            s_S[ph][pw] = i0;
            if (lh >= 8 * ty && lh < 8 * ty + 8 && lw >= 8 * tx && lw < 8 * tx + 8)
                Sout[gid] = (float)i0;
        }
    }
    __syncthreads();

    // ---- Phase C: fold (per pixel, all 16 channels) ----
    int pyL = tid >> 4, pxL = tid & 15;
    int y = y0 + pyL, x = x0 + pxL;
    const float* orgb = org + (size_t)b * CCH * OH * OW;
    float acc[CCH];
    #pragma unroll
    for (int c = 0; c < CCH; ++c) acc[c] = 0.f;
    int lhm = (y + 2) >> 1;
    int lwm = (x + 2) >> 1;
    int lh0 = lhm - 2 > 0 ? lhm - 2 : 0;
    int lh1 = lhm < 95 ? lhm : 95;
    int lw0 = lwm - 2 > 0 ? lwm - 2 : 0;
    int lw1 = lwm < 95 ? lwm : 95;
    for (int lh = lh0; lh <= lh1; ++lh) {
        int dy = y + 2 - 2 * lh;
        if (dy > 5) continue;
        for (int lw = lw0; lw <= lw1; ++lw) {
            int dx = x + 2 - 2 * lw;
            if (dx > 5) continue;
            int s  = s_S[lh - lhb][lw - lwb];
            int sh = s / 96, sw = s - sh * 96;
            int u = 2 * sh + dy - 2;
            int v = 2 * sw + dx - 2;
            if ((unsigned)u < (unsigned)OH && (unsigned)v < (unsigned)OW) {
                const float* p = orgb + u * OW + v;
                #pragma unroll
                for (int c = 0; c < CCH; ++c) acc[c] += p[(size_t)c * OH * OW];
            }
        }
    }
    #pragma unroll
    for (int c = 0; c < CCH; ++c)
        outT[(((size_t)(b * CCH + c)) * OH + y) * OW + x] = acc[c];
}

// --------------------------------------------------------------- launch ----
extern "C" void kernel_launch(void* const* d_in, const int* in_sizes, int n_in,
                              void* d_out, int out_size, void* d_ws, size_t ws_size,
                              hipStream_t stream) {
    const float* lrsr  = (const float*)d_in[0];
    const float* refsr = (const float*)d_in[1];
    const float* org   = (const float*)d_in[2];

    char* ws = (char*)d_ws;
    size_t o = 0;
    float* rinv     = (float*)(ws + o); o += (size_t)BATCH * LP * 4;
    float* bns      = (float*)(ws + o); o += (size_t)BATCH * LP * 4;
    float* pv1      = (float*)(ws + o); o += (size_t)BATCH * NRT2 * LP * 4;
    int*   pi1      = (int*)  (ws + o); o += (size_t)BATCH * NRT2 * LP * 4;
    float* pv2      = (float*)(ws + o); o += (size_t)BATCH * NRT2 * LP * 4;
    f16*   Abig     = (f16*)  (ws + o); o += (size_t)BATCH * LP * K3 * 2;
    f16*   Bbig     = (f16*)  (ws + o); o += (size_t)BATCH * LP * K3 * 2;

    float* outT = (float*)d_out;                          // 2*16*192*192
    float* outS = outT + (size_t)BATCH * CCH * OH * OW;   // 2*9216 as f32

    k_pack2<<<dim3(96, BATCH, 8), 256, 0, stream>>>(refsr, lrsr, rinv, bns, Abig, Bbig);
    k_mfma<<<dim3(NCB2 * NRT2 * BATCH), 1024, 0, stream>>>(Abig, Bbig, pv1, pi1, pv2);
    k_foldmerge<<<dim3(12, 12, BATCH), 256, 0, stream>>>(refsr, lrsr, rinv, pv1, pi1, pv2, bns,
                                                         org, outT, outS);
}

// Round 3
// 348.758 us; speedup vs baseline: 1.1205x; 1.1205x over previous
//
#include <hip/hip_runtime.h>
#include <float.h>

// SearchTransfer MI355X — R13. k_mfma REVERTED to R10 verbatim (186.5us
// proven; R11 counted-vmcnt -4%, R12 phase-split -18% => single-barrier
// chunk loop is the local optimum at 5 chunks x 16 waves x 1 block/CU).
// k_foldmerge rewritten for parallelism: 8x8 pixel tiles -> 1152 blocks
// (was 288: 32 CUs ran 2 blocks, 224 ran 1 -> 2x imbalance). Phase A split
// into 216-thread partial merges (6 rc each, ascending-rc first-wins
// preserved via the k_mfma-epilogue asymmetric combine) + 36-thread final.
// Phase C: one wave per 4-channel group (4x gather parallelism).
// k_pack2 unchanged (control).
// Split-f16 3-term GEMM (K'=320), top-2 guard tau=2^-6, pruned exact fixup.
// B=2, C=16, H=W=96, k=3,pad=1,stride=1, lv=2. L=9216, KF=144.
// out = [T_org (2*16*192*192 f32), S (2*9216 as f32)]

#define BATCH 2
#define CCH   16
#define HH    96
#define WW    96
#define LP    9216
#define KF    144
#define K3    320      // 5 chunks x 64 k' ; chunk = [hi32|lo32] of k-slice
#define OH    192
#define OW    192
#define NRT2  36       // row tiles of 256
#define NCB2  36       // col blocks of 256

typedef _Float16 f16;
typedef __attribute__((ext_vector_type(8))) _Float16 f16x8;
typedef __attribute__((ext_vector_type(4))) float    f32x4;

__device__ __forceinline__ void async16(const void* g, void* l) {
    __builtin_amdgcn_global_load_lds(
        (const __attribute__((address_space(1))) void*)g,
        (__attribute__((address_space(3))) void*)l, 16, 0, 0);
}

// ---------------------------------------------------- fused norm + pack ----
// UNCHANGED. Block = (py, batch, side*4+quarter). Norms bit-identical
// (zero-padded terms exact); writes 24 rows x 40 granules, layout:
// granule g: slice=g>>3, half=(g>>2)&1, j=g&3.
__global__ __launch_bounds__(256) void k_pack2(
        const float* __restrict__ ref, const float* __restrict__ lr,
        float* __restrict__ rinv, float* __restrict__ bns,
        f16* __restrict__ Abig, f16* __restrict__ Bbig) {
    __shared__ float imgS[CCH][3][26];   // x origin at global xi = q*24-1
    __shared__ float scl[24];
    int py = blockIdx.x, b = blockIdx.y;
    int side = blockIdx.z >> 2, q = blockIdx.z & 3;
    int tid = threadIdx.x;
    const float* img = (side ? lr : ref) + (size_t)b * CCH * HH * WW;

    for (int i = tid; i < CCH * 3 * 26; i += 256) {
        int c = i / 78, rem = i - c * 78;
        int rr = rem / 26, xx = rem - rr * 26;
        int y = py + rr - 1, xi = q * 24 - 1 + xx;
        float v = 0.f;
        if ((unsigned)y < (unsigned)HH && (unsigned)xi < (unsigned)WW)
            v = img[(c * HH + y) * WW + xi];
        imgS[c][rr][xx] = v;
    }
    __syncthreads();

    if (tid < 24) {
        int pxl = tid;
        float s = 0.f;
        for (int c = 0; c < CCH; ++c)
            #pragma unroll
            for (int dy = 0; dy < 3; ++dy)
                #pragma unroll
                for (int dx = 0; dx < 3; ++dx) {
                    float v = imgS[c][dy][pxl + dx];   // 0 when OOB: exact
                    s += v * v;
                }
        int gl = b * LP + py * 96 + q * 24 + pxl;
        if (side) { bns[gl] = 1024.0f * sqrtf(s); scl[pxl] = 1024.0f; }
        else { float r = 1.0f / fmaxf(sqrtf(s), 1e-12f); rinv[gl] = r; scl[pxl] = 1024.0f * r; }
    }
    __syncthreads();

    f16* dstb = (side ? Bbig : Abig) + (size_t)(b * LP + py * 96 + q * 24) * K3;
    for (int i = tid; i < 24 * 40; i += 256) {          // 40 granules/row
        int pxl = i / 40, g = i - pxl * 40;
        int chunk = g >> 3, half = (g >> 2) & 1, j = g & 3;
        int f0 = chunk * 32 + j * 8;                    // original k base
        float sc = scl[pxl];
        f16x8 o;
        #pragma unroll
        for (int e = 0; e < 8; ++e) {
            int f = f0 + e;                             // 0..159 (>=144 pad)
            float v = 0.f;
            if (f < KF) {
                int c = f / 9, r9 = f - c * 9;
                int dy = r9 / 3, dx = r9 - dy * 3;
                v = imgS[c][dy][pxl + dx] * sc;
            }
            f16 h = (f16)v;
            o[e] = half ? (f16)(v - (float)h) : h;
        }
        *(f16x8*)(dstb + (size_t)pxl * K3 + g * 8) = o;
    }
}

// -------------------------------------------------- MFMA GEMM + top-2 ------
// R10 verbatim (proven 186.5us). Single __syncthreads per chunk; prefetch
// ch+1 issued immediately after the drain -> full chunk of latency cover.
__global__ __launch_bounds__(1024) void k_mfma(
        const f16* __restrict__ Abig, const f16* __restrict__ Bbig,
        float* __restrict__ pv1, int* __restrict__ pi1, float* __restrict__ pv2) {
    __shared__ f16 smem[2][512 * 64];                  // 128 KB; rows 0-255=A, 256-511=B
    int tid = threadIdx.x, lane = tid & 63, w = tid >> 6;   // w: 0..15
    int wm = w & 3, wn = w >> 2;
    int l15 = lane & 15, quad = lane >> 4, l7 = lane & 7;

    int i = blockIdx.x;                // 0..2591
    int xcd = i & 7, slot = i >> 3;    // slot 0..323
    int cb = slot / 9;                 // col tile 0..35 (major)
    int brt = xcd * 9 + (slot - cb * 9);   // 0..71
    int b = brt / NRT2, rt = brt - b * NRT2;
    int r0 = rt * 256, c0 = cb * 256;

    int srow = lane >> 3;              // row within group
    int sg   = (lane & 7) ^ srow;      // source granule (self-inverse swizzle)
    const f16* gsrc[4];
    int ldsbyte[4];                    // wave-uniform byte offset in one buffer
    #pragma unroll
    for (int j = 0; j < 4; ++j) {
        int G = w * 4 + j;             // 0..63
        int row8 = G * 8 + srow;       // 0..511 (A rows then B rows)
        const f16* base = (row8 < 256)
            ? Abig + (size_t)(b * LP + r0 + row8) * K3
            : Bbig + (size_t)(b * LP + c0 + (row8 - 256)) * K3;
        gsrc[j] = base + sg * 8;
        ldsbyte[j] = G * 1024;         // G*8 rows * 128 B/row
    }
    int arow[4], brow[4];              // frag row byte offsets (row stride 128 B)
    #pragma unroll
    for (int t = 0; t < 4; ++t) {
        arow[t] = (wm * 64 + t * 16 + l15) * 128;
        brow[t] = (256 + wn * 64 + t * 16 + l15) * 128;
    }

    f32x4 acc[4][4];
    #pragma unroll
    for (int ii = 0; ii < 4; ++ii)
        #pragma unroll
        for (int j = 0; j < 4; ++j) { acc[ii][j][0]=0.f; acc[ii][j][1]=0.f; acc[ii][j][2]=0.f; acc[ii][j][3]=0.f; }

    // prologue: chunk 0 -> buf 0
    #pragma unroll
    for (int j = 0; j < 4; ++j) async16(gsrc[j], (char*)smem[0] + ldsbyte[j]);

    for (int ch = 0; ch < 5; ++ch) {
        __syncthreads();               // drains own DMA; buf[ch&1] ready
        if (ch < 4) {
            #pragma unroll
            for (int j = 0; j < 4; ++j)
                async16(gsrc[j] + (ch + 1) * 64, (char*)smem[(ch + 1) & 1] + ldsbyte[j]);
        }
        const char* buf = (const char*)smem[ch & 1];
        int ph0 = ((quad) ^ l7) << 4;          // ks=0 granules: hi slice
        int ph1 = ((4 + quad) ^ l7) << 4;      // ks=1 granules: lo slice
        f16x8 af0[4], bf0[4], bf1[4], af1[4];
        // phase 1: hi*hi
        #pragma unroll
        for (int t = 0; t < 4; ++t) af0[t] = *(const f16x8*)(buf + arow[t] + ph0);
        #pragma unroll
        for (int t = 0; t < 4; ++t) bf0[t] = *(const f16x8*)(buf + brow[t] + ph0);
        #pragma unroll
        for (int rtt = 0; rtt < 4; ++rtt)
            #pragma unroll
            for (int ct = 0; ct < 4; ++ct)
                acc[rtt][ct] = __builtin_amdgcn_mfma_f32_16x16x32_f16(af0[rtt], bf0[ct], acc[rtt][ct], 0, 0, 0);
        // phase 2: hi*lo
        #pragma unroll
        for (int t = 0; t < 4; ++t) bf1[t] = *(const f16x8*)(buf + brow[t] + ph1);
        #pragma unroll
        for (int rtt = 0; rtt < 4; ++rtt)
            #pragma unroll
            for (int ct = 0; ct < 4; ++ct)
                acc[rtt][ct] = __builtin_amdgcn_mfma_f32_16x16x32_f16(af0[rtt], bf1[ct], acc[rtt][ct], 0, 0, 0);
        // phase 3: lo*hi
        #pragma unroll
        for (int t = 0; t < 4; ++t) af1[t] = *(const f16x8*)(buf + arow[t] + ph1);
        #pragma unroll
        for (int rtt = 0; rtt < 4; ++rtt)
            #pragma unroll
            for (int ct = 0; ct < 4; ++ct)
                acc[rtt][ct] = __builtin_amdgcn_mfma_f32_16x16x32_f16(af1[rtt], bf0[ct], acc[rtt][ct], 0, 0, 0);
    }
    __syncthreads();                   // smem reads done -> overlay epilogue scratch

    float* sv1 = (float*)smem;                         // [4][256]
    int*   si1 = (int*)  ((char*)smem + 4096);
    float* sv2 = (float*)((char*)smem + 8192);

    int rbase = r0 + wm * 64 + (quad << 2);
    #pragma unroll
    for (int ct = 0; ct < 4; ++ct) {
        float v1 = -FLT_MAX, v2 = -FLT_MAX; int i1 = 0;
        #pragma unroll
        for (int rtt = 0; rtt < 4; ++rtt)
            #pragma unroll
            for (int e = 0; e < 4; ++e) {              // ascending rows; strict > = first wins
                float v = acc[rtt][ct][e];
                int rg = rbase + rtt * 16 + e;
                if (v > v1) { v2 = v1; v1 = v; i1 = rg; }
                else if (v > v2) v2 = v;
            }
        #pragma unroll
        for (int off = 16; off < 64; off <<= 1) {      // reduce over quad (rows)
            float ov1 = __shfl_xor(v1, off, 64);
            int   oi1 = __shfl_xor(i1, off, 64);
            float ov2 = __shfl_xor(v2, off, 64);
            if (ov1 > v1 || (ov1 == v1 && oi1 < i1)) { v2 = fmaxf(v1, ov2); v1 = ov1; i1 = oi1; }
            else v2 = fmaxf(v2, ov1);
        }
        if (quad == 0) {
            int col = wn * 64 + ct * 16 + l15;
            sv1[wm * 256 + col] = v1; si1[wm * 256 + col] = i1; sv2[wm * 256 + col] = v2;
        }
    }
    __syncthreads();
    if (tid < 256) {
        int col = tid;
        float v1 = sv1[col]; int i1 = si1[col]; float v2 = sv2[col];
        #pragma unroll
        for (int m = 1; m < 4; ++m) {                  // ascending wm = ascending rows
            float ov1 = sv1[m * 256 + col]; int oi1 = si1[m * 256 + col]; float ov2 = sv2[m * 256 + col];
            if (ov1 > v1) { v2 = fmaxf(v1, ov2); v1 = ov1; i1 = oi1; }
            else v2 = fmaxf(v2, ov1);
        }
        size_t o = ((size_t)(b * NRT2 + rt)) * LP + c0 + col;
        pv1[o] = v1; pi1[o] = i1; pv2[o] = v2;
    }
}

// -------------------------------------- fused merge + fixup + fold ---------
// R13: 8x8 pixel tiles -> dim3(24,24,2)=1152 blocks (was 288, imbalanced).
// Patch window 6x6 (36 patches). Phase A1: 216 threads, each merges 6 rc
// values for one patch (partial, ascending rc). Phase A2: 36 threads merge
// the 6 partials in ascending-r order (first-wins combine identical to
// k_mfma epilogue), flag iff gap < tau, owner (4x4 center) writes Sout.
// Phase B: exact pruned fixup, unchanged logic (<=4-block dup, idempotent).
// Phase C: wave w handles channels 4w..4w+3 for all 64 pixels (4x gather
// parallelism vs 1-thread-per-pixel).
__global__ __launch_bounds__(256) void k_foldmerge(
        const float* __restrict__ refimg, const float* __restrict__ lrimg,
        const float* __restrict__ rinv,
        const float* __restrict__ pv1, const int* __restrict__ pi1,
        const float* __restrict__ pv2, const float* __restrict__ bns,
        const float* __restrict__ org,
        float* __restrict__ outT, float* __restrict__ Sout) {
    __shared__ int   s_S[6][6];
    __shared__ int   s_flag[36];
    __shared__ int   s_nflag;
    __shared__ float pa_v1[36][6];
    __shared__ int   pa_i1[36][6];
    __shared__ float pa_v2[36][6];
    __shared__ float bcol[KF];
    __shared__ float spv[NRT2];
    __shared__ float red[4]; __shared__ int redi[4];
    int tx = blockIdx.x, ty = blockIdx.y, b = blockIdx.z;
    int x0 = tx * 8, y0 = ty * 8;
    int lhb = 4 * ty - 1; if (lhb < 0) lhb = 0;
    int lwb = 4 * tx - 1; if (lwb < 0) lwb = 0;
    int lhe = 4 * ty + 4; if (lhe > 95) lhe = 95;
    int lwe = 4 * tx + 4; if (lwe > 95) lwe = 95;
    int tid = threadIdx.x;

    if (tid == 0) s_nflag = 0;

    // ---- Phase A1: partial merges (patch p = tid/6, rc in [6r, 6r+6)) ----
    if (tid < 216) {
        int p = tid / 6, r = tid - p * 6;
        int ph = p / 6, pw = p - ph * 6;
        int lh = lhb + ph, lw = lwb + pw;
        if (lh <= lhe && lw <= lwe) {
            int col = lh * 96 + lw;
            float v1 = -FLT_MAX, v2 = -FLT_MAX; int i1 = 0;
            #pragma unroll
            for (int k = 0; k < 6; ++k) {              // ascending rc: first-wins
                int rc = r * 6 + k;
                size_t o = ((size_t)(b * NRT2 + rc)) * LP + col;
                float cv1 = pv1[o]; int ci1 = pi1[o]; float cv2 = pv2[o];
                if (cv1 > v1) { v2 = fmaxf(v1, cv2); v1 = cv1; i1 = ci1; }
                else v2 = fmaxf(v2, cv1);
            }
            pa_v1[p][r] = v1; pa_i1[p][r] = i1; pa_v2[p][r] = v2;
        }
    }
    __syncthreads();

    // ---- Phase A2: final merge over partials (ascending r = ascending rc) ----
    if (tid < 36) {
        int ph = tid / 6, pw = tid - ph * 6;
        int lh = lhb + ph, lw = lwb + pw;
        if (lh <= lhe && lw <= lwe) {
            int col = lh * 96 + lw;
            float v1 = pa_v1[tid][0]; int i1 = pa_i1[tid][0]; float v2 = pa_v2[tid][0];
            #pragma unroll
            for (int r = 1; r < 6; ++r) {              // later partials win on strict >
                float ov1 = pa_v1[tid][r]; int oi1 = pa_i1[tid][r]; float ov2 = pa_v2[tid][r];
                if (ov1 > v1) { v2 = fmaxf(v1, ov2); v1 = ov1; i1 = oi1; }
                else v2 = fmaxf(v2, ov1);
            }
            s_S[ph][pw] = i1;
            float tau = bns[b * LP + col] * 0.015625f; // 2^-6
            if (v1 - v2 < tau) { int k = atomicAdd(&s_nflag, 1); s_flag[k] = tid; }
            if (lh >= 4 * ty && lh < 4 * ty + 4 && lw >= 4 * tx && lw < 4 * tx + 4)
                Sout[b * LP + col] = (float)i1;        // owner write (partition)
        }
    }
    __syncthreads();

    // ---- Phase B: exact fixup for flagged patches (rare) ----
    int nf = s_nflag;
    for (int fi = 0; fi < nf; ++fi) {
        int pt = s_flag[fi];
        int ph = pt / 6, pw = pt - ph * 6;
        int lh = lhb + ph, lw = lwb + pw;
        int col = lh * 96 + lw, gid = b * LP + col;
        __syncthreads();                               // protect bcol/spv reuse
        if (tid < KF) {
            int c = tid / 9, r = tid - c * 9;
            int dy = r / 3, dx = r - dy * 3;
            int y = lh + dy - 1, x = lw + dx - 1;
            float v = 0.f;
            if ((unsigned)y < (unsigned)HH && (unsigned)x < (unsigned)WW)
                v = lrimg[((size_t)(b * CCH + c) * HH + y) * WW + x];
            bcol[tid] = v;
        }
        if (tid < NRT2) spv[tid] = pv1[((size_t)(b * NRT2 + tid)) * LP + col];
        __syncthreads();
        float v1 = -FLT_MAX;
        for (int rc = 0; rc < NRT2; ++rc) v1 = fmaxf(v1, spv[rc]);
        float thresh = v1 - bns[gid] * 0.015625f;
        float best = -FLT_MAX; int bi = 0x7fffffff;
        for (int rc = 0; rc < NRT2; ++rc) {            // ascending rows
            if (spv[rc] < thresh) continue;            // prune (uniform)
            int row = rc * 256 + tid;
            int py = row / WW, px = row - py * WW;
            float s = 0.f;
            for (int c = 0; c < CCH; ++c) {
                const float* ic = refimg + (size_t)(b * CCH + c) * HH * WW;
                #pragma unroll
                for (int dy = 0; dy < 3; ++dy) {
                    int y = py + dy - 1;
                    if ((unsigned)y >= (unsigned)HH) continue;
                    #pragma unroll
                    for (int dx = 0; dx < 3; ++dx) {
                        int x = px + dx - 1;
                        if ((unsigned)x >= (unsigned)WW) continue;
                        s = fmaf(ic[y * WW + x], bcol[c * 9 + dy * 3 + dx], s);
                    }
                }
            }
            s *= rinv[b * LP + row];
            if (s > best || (s == best && row < bi)) { best = s; bi = row; }
        }
        #pragma unroll
        for (int off = 1; off < 64; off <<= 1) {
            float ov = __shfl_xor(best, off, 64);
            int   oi = __shfl_xor(bi, off, 64);
            if (ov > best || (ov == best && oi < bi)) { best = ov; bi = oi; }
        }
        if ((tid & 63) == 0) { red[tid >> 6] = best; redi[tid >> 6] = bi; }
        __syncthreads();
        if (tid == 0) {
            float b0 = red[0]; int i0 = redi[0];
            for (int k = 1; k < 4; ++k)
                if (red[k] > b0 || (red[k] == b0 && redi[k] < i0)) { b0 = red[k]; i0 = redi[k]; }
            s_S[ph][pw] = i0;
            if (lh >= 4 * ty && lh < 4 * ty + 4 && lw >= 4 * tx && lw < 4 * tx + 4)
                Sout[gid] = (float)i0;
        }
    }
    __syncthreads();

    // ---- Phase C: fold; wave w = channels 4w..4w+3, lane = pixel ----
    int wid = tid >> 6, pix = tid & 63;
    int pyL = pix >> 3, pxL = pix & 7;
    int y = y0 + pyL, x = x0 + pxL;
    const float* orgb = org + ((size_t)b * CCH + wid * 4) * OH * OW;
    float acc[4];
    #pragma unroll
    for (int c = 0; c < 4; ++c) acc[c] = 0.f;
    int lhm = (y + 2) >> 1;
    int lwm = (x + 2) >> 1;
    int lh0 = lhm - 2 > 0 ? lhm - 2 : 0;
    int lh1 = lhm < 95 ? lhm : 95;
    int lw0 = lwm - 2 > 0 ? lwm - 2 : 0;
    int lw1 = lwm < 95 ? lwm : 95;
    for (int lh = lh0; lh <= lh1; ++lh) {
        int dy = y + 2 - 2 * lh;
        if (dy > 5) continue;
        for (int lw = lw0; lw <= lw1; ++lw) {
            int dx = x + 2 - 2 * lw;
            if (dx > 5) continue;
            int s  = s_S[lh - lhb][lw - lwb];
            int sh = s / 96, sw = s - sh * 96;
            int u = 2 * sh + dy - 2;
            int v = 2 * sw + dx - 2;
            if ((unsigned)u < (unsigned)OH && (unsigned)v < (unsigned)OW) {
                const float* p = orgb + u * OW + v;
                #pragma unroll
                for (int c = 0; c < 4; ++c) acc[c] += p[(size_t)c * OH * OW];
            }
        }
    }
    #pragma unroll
    for (int c = 0; c < 4; ++c)
        outT[(((size_t)(b * CCH + wid * 4 + c)) * OH + y) * OW + x] = acc[c];
}

// --------------------------------------------------------------- launch ----
extern "C" void kernel_launch(void* const* d_in, const int* in_sizes, int n_in,
                              void* d_out, int out_size, void* d_ws, size_t ws_size,
                              hipStream_t stream) {
    const float* lrsr  = (const float*)d_in[0];
    const float* refsr = (const float*)d_in[1];
    const float* org   = (const float*)d_in[2];

    char* ws = (char*)d_ws;
    size_t o = 0;
    float* rinv     = (float*)(ws + o); o += (size_t)BATCH * LP * 4;
    float* bns      = (float*)(ws + o); o += (size_t)BATCH * LP * 4;
    float* pv1      = (float*)(ws + o); o += (size_t)BATCH * NRT2 * LP * 4;
    int*   pi1      = (int*)  (ws + o); o += (size_t)BATCH * NRT2 * LP * 4;
    float* pv2      = (float*)(ws + o); o += (size_t)BATCH * NRT2 * LP * 4;
    f16*   Abig     = (f16*)  (ws + o); o += (size_t)BATCH * LP * K3 * 2;
    f16*   Bbig     = (f16*)  (ws + o); o += (size_t)BATCH * LP * K3 * 2;

    float* outT = (float*)d_out;                          // 2*16*192*192
    float* outS = outT + (size_t)BATCH * CCH * OH * OW;   // 2*9216 as f32

    k_pack2<<<dim3(96, BATCH, 8), 256, 0, stream>>>(refsr, lrsr, rinv, bns, Abig, Bbig);
    k_mfma<<<dim3(NCB2 * NRT2 * BATCH), 1024, 0, stream>>>(Abig, Bbig, pv1, pi1, pv2);
    k_foldmerge<<<dim3(24, 24, BATCH), 256, 0, stream>>>(refsr, lrsr, rinv, pv1, pi1, pv2, bns,
                                                         org, outT, outS);
}